// Round 9
// baseline (656.896 us; speedup 1.0000x reference)
//
#include <hip/hip_runtime.h>
#include <math.h>

// Problem constants (B=4, Ci=128, Cg=64, H=W=128), all fp32.
#define BB   4
#define CI   128
#define CG   64
#define CIN  192
#define HH   128
#define WW   128
#define PP   16384
#define EPSN 1e-5f

typedef unsigned short u16;
typedef unsigned int   u32;
typedef __attribute__((ext_vector_type(8))) short bf16x8;
typedef __attribute__((ext_vector_type(4))) float f32x4;

__device__ __forceinline__ u16 f2bf(float x) {
    union { float f; u32 u; } a; a.f = x;
    u32 u = a.u;
    return (u16)((u + 0x7FFFu + ((u >> 16) & 1u)) >> 16);   // RNE
}
__device__ __forceinline__ float bf2f(u16 h) {
    union { u32 u; float f; } a; a.u = ((u32)h) << 16; return a.f;
}
// XOR-swizzle for [px][c] bf16 row-images (256B per px row).
__device__ __forceinline__ u32 swz(u32 o) { return o ^ ((o >> 4) & 0x70u); }
// Xs slot swizzle: slot s in [0,4) within a 64B channel-row cc.
__device__ __forceinline__ int xslot(int cc) { return (cc >> 1) & 3; }

__device__ __forceinline__ void gld_lds16(const void* g, void* l) {
    __builtin_amdgcn_global_load_lds(
        (const __attribute__((address_space(1))) void*)g,
        (__attribute__((address_space(3))) void*)l, 16, 0, 0);
}
// XCD-aware block->row swizzle for grid.x == 128 (bijective).
__device__ __forceinline__ int yswz(int bid) {
    return ((bid & 7) << 4) | (bid >> 3);
}

// ---------------------------------------------------------------------------
// P1: pad(1) + NCHW->NHWC transpose + RNE bf16 (single image, no lo half).
// ---------------------------------------------------------------------------
__global__ __launch_bounds__(256) void k_pack(
    const float* __restrict__ src0, int nch0,
    const float* __restrict__ src1, int nch1,
    u16* __restrict__ dst, int cinp)
{
    const int rr = blockIdx.x;   // 0..129
    const int b  = blockIdx.y;
    const int t  = threadIdx.x;
    u16* rh = dst + ((size_t)b * 130 + rr) * 130 * cinp;

    if (rr == 0 || rr == 129) {
        u32* rh4 = (u32*)rh;
        const int tot = 130 * cinp / 2;
        for (int i = t; i < tot; i += 256) rh4[i] = 0u;
        return;
    }
    const int y = rr - 1;
    for (int i = t; i < cinp; i += 256) {
        rh[i] = 0;
        rh[129 * cinp + i] = 0;
    }

    __shared__ float xs[32][129];
    for (int ck = 0; ck < cinp / 32; ++ck) {
        __syncthreads();
        for (int i = t; i < 32 * 128; i += 256) {
            const int ch = i >> 7, col = i & 127;
            const int c = ck * 32 + ch;
            const float* sp = (c < nch0)
                ? src0 + ((size_t)b * nch0 + c) * PP
                : src1 + ((size_t)b * nch1 + (c - nch0)) * PP;
            xs[ch][col] = sp[y * WW + col];
        }
        __syncthreads();
        for (int i = t; i < 512; i += 256) {
            const int col = i >> 2, oct = i & 3;
            u16 hh[8];
#pragma unroll
            for (int j = 0; j < 8; ++j) hh[j] = f2bf(xs[oct * 8 + j][col]);
            const size_t off = (size_t)(col + 1) * cinp + ck * 32 + oct * 8;
            uint4 vh;
            vh.x = (u32)hh[0] | ((u32)hh[1] << 16); vh.y = (u32)hh[2] | ((u32)hh[3] << 16);
            vh.z = (u32)hh[4] | ((u32)hh[5] << 16); vh.w = (u32)hh[6] | ((u32)hh[7] << 16);
            *(uint4*)(rh + off) = vh;
        }
    }
}

// ---------------------------------------------------------------------------
// P2: 3x3 weight rearrange + hi/lo split. dst[half][mb][ck][tap][oc][kk32].
// ---------------------------------------------------------------------------
__global__ __launch_bounds__(256) void k_wpack(
    const float* __restrict__ w0, const float* __restrict__ w1,
    u16* __restrict__ dst, int nmb, int nck, int cin)
{
    const int total = nmb * nck * 9 * 128 * 4;
    const int idx = blockIdx.x * 256 + threadIdx.x;
    if (idx >= total) return;
    const int oct = idx & 3; int r2 = idx >> 2;
    const int oc = r2 & 127; r2 >>= 7;
    const int tap = r2 % 9; r2 /= 9;
    const int ck = r2 % nck; r2 /= nck;
    const int mb = r2;
    const float* w = mb ? w1 : w0;
    u16 hh[8], ll[8];
#pragma unroll
    for (int j = 0; j < 8; ++j) {
        const int c = ck * 32 + oct * 8 + j;
        const float v = w[((size_t)oc * cin + c) * 9 + tap];
        const u16 h = f2bf(v);
        hh[j] = h; ll[j] = f2bf(v - bf2f(h));
    }
    const size_t halfs = (size_t)nmb * nck * 9 * 128 * 32;
    const size_t base = ((((size_t)mb * nck + ck) * 9 + tap) * 128 + oc) * 32 + oct * 8;
    uint4 vh, vl;
    vh.x = (u32)hh[0] | ((u32)hh[1] << 16); vh.y = (u32)hh[2] | ((u32)hh[3] << 16);
    vh.z = (u32)hh[4] | ((u32)hh[5] << 16); vh.w = (u32)hh[6] | ((u32)hh[7] << 16);
    vl.x = (u32)ll[0] | ((u32)ll[1] << 16); vl.y = (u32)ll[2] | ((u32)ll[3] << 16);
    vl.z = (u32)ll[4] | ((u32)ll[5] << 16); vl.w = (u32)ll[6] | ((u32)ll[7] << 16);
    *(uint4*)(dst + base) = vh;
    *(uint4*)(dst + halfs + base) = vl;
}

// ---------------------------------------------------------------------------
// P4: w12 -> w12p[half][tap][cc][c] split bf16.
// ---------------------------------------------------------------------------
__global__ __launch_bounds__(256) void k_wpack12(
    const float* __restrict__ w12, u16* __restrict__ dst)
{
    const int idx = blockIdx.x * 256 + threadIdx.x;   // 18432
    if (idx >= 18432) return;
    const int oct = idx & 15;
    const int g   = idx >> 4;
    const int cc  = g / 9, tap = g % 9;
    u16 hh[8], ll[8];
#pragma unroll
    for (int j = 0; j < 8; ++j) {
        const float v = w12[(size_t)g * 128 + oct * 8 + j];
        const u16 h = f2bf(v);
        hh[j] = h; ll[j] = f2bf(v - bf2f(h));
    }
    const size_t base = ((size_t)(tap * 128 + cc)) * 128 + oct * 8;
    uint4 vh, vl;
    vh.x = (u32)hh[0] | ((u32)hh[1] << 16); vh.y = (u32)hh[2] | ((u32)hh[3] << 16);
    vh.z = (u32)hh[4] | ((u32)hh[5] << 16); vh.w = (u32)hh[6] | ((u32)hh[7] << 16);
    vl.x = (u32)ll[0] | ((u32)ll[1] << 16); vl.y = (u32)ll[2] | ((u32)ll[3] << 16);
    vl.z = (u32)ll[4] | ((u32)ll[5] << 16); vl.w = (u32)ll[6] | ((u32)ll[7] << 16);
    *(uint4*)(dst + base) = vh;
    *(uint4*)(dst + 147456 + base) = vl;
}

#define LOADA(tapv, AH, AL) do {                                              \
    const size_t abase_ = (((size_t)mb * NCK + ck) * 9 + (tapv)) * 4096;      \
    _Pragma("unroll")                                                         \
    for (int f_ = 0; f_ < 4; ++f_) {                                          \
        const size_t ao_ = abase_ + (size_t)(wm * 64 + f_ * 16 + l15) * 32 + kg * 8; \
        AH[f_] = *(const bf16x8*)(wA + ao_);                                  \
        AL[f_] = *(const bf16x8*)(wA + WHALF + ao_);                          \
    } } while (0)

#define LOADB(tapv, BV) do {                                                  \
    const int dy_ = (tapv) / 3, dx_ = (tapv) % 3;                             \
    _Pragma("unroll")                                                         \
    for (int f_ = 0; f_ < 4; ++f_) {                                          \
        const int cc_ = wn * 64 + f_ * 16 + l15 + dx_;                        \
        BV[f_] = *(const bf16x8*)(bbase + dy_ * 9216 + cc_ * 64               \
                                  + ((kg ^ xslot(cc_)) << 4));                \
    } } while (0)

// ---------------------------------------------------------------------------
// 3x3 conv implicit-GEMM MFMA, 2-pass (A split hi/lo, B plain bf16).
// Double-buffered X chunks (counted vmcnt(6), raw barriers), tap+1 A/B
// register prefetch, pass-major MFMA order, XCD y-swizzle.
// ---------------------------------------------------------------------------
template<int NCK, bool DUAL>
__global__ __launch_bounds__(256, 2) void k_conv_mfma(
    const u16* __restrict__ xin, const u16* __restrict__ wA,
    const float* __restrict__ bias0, const float* __restrict__ bias1,
    const float* __restrict__ bng, const float* __restrict__ bnb,
    const float* __restrict__ bnm, const float* __restrict__ bnv,
    float* __restrict__ dstf, float* __restrict__ bnout,
    u16* __restrict__ y1img)
{
    constexpr int CINP = NCK * 32;
    constexpr size_t WHALF = (size_t)(DUAL ? 2 : 1) * NCK * 9 * 128 * 32;

    __shared__ char smem[55296];   // 2 bufs x 3 rows x 144cc x 32ch x 2B

    const int t    = threadIdx.x;
    const int wave = t >> 6;
    const int lane = t & 63;
    const int wm   = wave >> 1, wn = wave & 1;
    const int y    = yswz(blockIdx.x);
    const int mb   = blockIdx.y;
    const int b    = blockIdx.z;
    const int l15  = lane & 15;
    const int kg   = lane >> 4;

    f32x4 acc[4][4];
    if (DUAL) {
        const float* bp = mb ? bias1 : bias0;
#pragma unroll
        for (int fm = 0; fm < 4; ++fm) {
            const int ocb = wm * 64 + fm * 16 + kg * 4;
#pragma unroll
            for (int j = 0; j < 4; ++j) {
                const float bv = bp[ocb + j];
#pragma unroll
                for (int fn = 0; fn < 4; ++fn) acc[fm][fn][j] = bv;
            }
        }
    } else {
#pragma unroll
        for (int fm = 0; fm < 4; ++fm)
#pragma unroll
            for (int fn = 0; fn < 4; ++fn)
#pragma unroll
                for (int j = 0; j < 4; ++j) acc[fm][fn][j] = 0.0f;
    }

    const size_t xrow = (size_t)130 * CINP;

    // stage chunk c into buffer bsel: 27 x 1KB, pre-swizzled source
    #define STAGE(c, bsel) do {                                               \
        for (int idx_ = wave; idx_ < 27; idx_ += 4) {                         \
            const int r_ = idx_ / 9, iss_ = idx_ % 9;                         \
            const u16* gb_ = xin + ((size_t)b * 130 + (y + r_)) * xrow + (c) * 32; \
            const int cc_ = iss_ * 16 + (lane >> 2);                          \
            const int rb_ = ((lane & 3) << 4) ^ (xslot(cc_) << 4);            \
            gld_lds16((const char*)gb_ + (size_t)cc_ * (CINP * 2) + rb_,      \
                      smem + (bsel) * 27648 + r_ * 9216 + iss_ * 1024);       \
        } } while (0)

    STAGE(0, 0);
    int cur = 0;
    for (int ck = 0; ck < NCK; ++ck) {
        STAGE(ck + 1 < NCK ? ck + 1 : 0, cur ^ 1);   // dummy wrap at last ck
        asm volatile("s_waitcnt vmcnt(6)" ::: "memory");
        __builtin_amdgcn_s_barrier();

        const char* bbase = smem + cur * 27648;
        bf16x8 ahC[4], alC[4], bC[4];
        LOADA(0, ahC, alC);
        LOADB(0, bC);
#pragma unroll
        for (int tap = 0; tap < 9; ++tap) {
            bf16x8 ahN[4], alN[4], bN[4];
            if (tap < 8) { LOADA(tap + 1, ahN, alN); LOADB(tap + 1, bN); }
            // pass-major: 16 independent accs between chained MFMAs
#pragma unroll
            for (int fm = 0; fm < 4; ++fm)
#pragma unroll
                for (int fn = 0; fn < 4; ++fn)
                    acc[fm][fn] = __builtin_amdgcn_mfma_f32_16x16x32_bf16(
                        alC[fm], bC[fn], acc[fm][fn], 0, 0, 0);
#pragma unroll
            for (int fm = 0; fm < 4; ++fm)
#pragma unroll
                for (int fn = 0; fn < 4; ++fn)
                    acc[fm][fn] = __builtin_amdgcn_mfma_f32_16x16x32_bf16(
                        ahC[fm], bC[fn], acc[fm][fn], 0, 0, 0);
            if (tap < 8) {
#pragma unroll
                for (int f = 0; f < 4; ++f) {
                    ahC[f] = ahN[f]; alC[f] = alN[f]; bC[f] = bN[f];
                }
            }
        }
        __builtin_amdgcn_s_barrier();   // all reads of buf done before overwrite
        cur ^= 1;
    }
    asm volatile("s_waitcnt vmcnt(0)" ::: "memory");   // drain dummy stage
    #undef STAGE

    if (DUAL && mb == 0) {
        // y1: ReLU + RNE bf16 swizzled [px][c] image -> coalesced 32KB store
        __builtin_amdgcn_s_barrier();   // all waves' DMAs drained
        u16* img = (u16*)smem;
#pragma unroll
        for (int fm = 0; fm < 4; ++fm)
#pragma unroll
            for (int fn = 0; fn < 4; ++fn) {
                const int px = wn * 64 + fn * 16 + l15;
                const int c0 = wm * 64 + fm * 16 + kg * 4;
                u16 hh[4];
#pragma unroll
                for (int j = 0; j < 4; ++j)
                    hh[j] = f2bf(fmaxf(acc[fm][fn][j], 0.0f));
                const u32 off = swz((u32)(px * 256 + c0 * 2));
                uint2 vh;
                vh.x = (u32)hh[0] | ((u32)hh[1] << 16);
                vh.y = (u32)hh[2] | ((u32)hh[3] << 16);
                *(uint2*)((char*)img + off) = vh;
            }
        __builtin_amdgcn_s_barrier();
        uint4* gd = (uint4*)(y1img + ((size_t)b * 128 + y) * 16384);
        const uint4* s4 = (const uint4*)smem;
        for (int i = t; i < 2048; i += 256) gd[i] = s4[i];
        return;
    }

    // fp32 paths (DUAL mb=1 -> y2o; !DUAL -> BN+ReLU -> out)
    float* dst = DUAL ? dstf : bnout;
#pragma unroll
    for (int fm = 0; fm < 4; ++fm) {
#pragma unroll
        for (int j = 0; j < 4; ++j) {
            const int oc = wm * 64 + fm * 16 + kg * 4 + j;
            float sc = 1.0f, sh = 0.0f;
            if (!DUAL) {
                sc = bng[oc] * rsqrtf(bnv[oc] + EPSN);
                sh = bnb[oc] - bnm[oc] * sc;
            }
            const size_t obase = ((size_t)b * CI + oc) * PP + (size_t)y * WW;
#pragma unroll
            for (int fn = 0; fn < 4; ++fn) {
                const int px = wn * 64 + fn * 16 + l15;
                float v = acc[fm][fn][j];
                if (!DUAL) v = fmaf(v, sc, sh);
                dst[obase + px] = fmaxf(v, 0.0f);
            }
        }
    }
}

// ---------------------------------------------------------------------------
// K2: global average pool of y2 -> pooled[b][c]
// ---------------------------------------------------------------------------
__global__ __launch_bounds__(256) void k_pool(
    const float* __restrict__ y2, float* __restrict__ pooled)
{
    const int c = blockIdx.x, b = blockIdx.y, t = threadIdx.x;
    const float* src = y2 + ((size_t)b * CI + c) * PP;
    float s = 0.0f;
    for (int i = t; i < PP; i += 256) s += src[i];
    __shared__ float red[256];
    red[t] = s;
    __syncthreads();
    for (int st = 128; st > 0; st >>= 1) {
        if (t < st) red[t] += red[t + st];
        __syncthreads();
    }
    if (t == 0) pooled[b * CI + c] = red[0] * (1.0f / PP);
}

// ---------------------------------------------------------------------------
// K3: w22o = w22 . pooled + b22 -> split bf16 [half][b][i][j]
// ---------------------------------------------------------------------------
__global__ __launch_bounds__(256) void k_w22(
    const float* __restrict__ w22, const float* __restrict__ b22,
    const float* __restrict__ pooled, u16* __restrict__ w22p)
{
    const int b = blockIdx.y;
    const int o = blockIdx.x * 256 + threadIdx.x;
    __shared__ float pl[CI];
    if (threadIdx.x < CI) pl[threadIdx.x] = pooled[b * CI + threadIdx.x];
    __syncthreads();
    const float4* wr = (const float4*)(w22 + (size_t)o * CI);
    float acc = b22[o];
#pragma unroll 8
    for (int c4 = 0; c4 < CI / 4; ++c4) {
        const float4 w = wr[c4];
        acc += w.x * pl[c4 * 4 + 0] + w.y * pl[c4 * 4 + 1] +
               w.z * pl[c4 * 4 + 2] + w.w * pl[c4 * 4 + 3];
    }
    const u16 h = f2bf(acc);
    w22p[(size_t)b * 16384 + o] = h;
    w22p[65536 + (size_t)b * 16384 + o] = f2bf(acc - bf2f(h));
}

// ---------------------------------------------------------------------------
// K4: guided conv via MFMA (2-pass), fold with fp32 x, BN1+ReLU -> locp image
// ---------------------------------------------------------------------------
__global__ __launch_bounds__(256, 2) void k_guided_mfma(
    const float* __restrict__ input,
    const u16* __restrict__ y1img,   // [b][y][16384] swz image
    const u16* __restrict__ w12p,    // [half +147456][tap][cc][c]
    const float* __restrict__ b12,
    const float* __restrict__ g1, const float* __restrict__ be1,
    const float* __restrict__ m1, const float* __restrict__ v1,
    u16* __restrict__ locp)          // same image format
{
    __shared__ char smem[32768];
    const int t = threadIdx.x;
    const int wave = t >> 6, lane = t & 63;
    const int wm = wave >> 1, wn = wave & 1;
    const int l15 = lane & 15, kg = lane >> 4;
    const int y = yswz(blockIdx.x), b = blockIdx.y;

    {
        const u16* gb = y1img + ((size_t)b * 128 + y) * 16384;
        for (int iss = wave; iss < 32; iss += 4)
            gld_lds16((const char*)gb + iss * 1024 + lane * 16,
                      smem + iss * 1024);
    }
    asm volatile("s_waitcnt vmcnt(0)" ::: "memory");
    __syncthreads();

    f32x4 accL[4][4];
#pragma unroll
    for (int fm = 0; fm < 4; ++fm)
#pragma unroll
        for (int fn = 0; fn < 4; ++fn)
#pragma unroll
            for (int j = 0; j < 4; ++j) accL[fm][fn][j] = 0.0f;

    const float* xb = input + (size_t)b * CI * PP;

    for (int tap = 0; tap < 9; ++tap) {
        const int ry  = y + tap / 3 - 1;
        const int dxo = tap % 3 - 1;
        if ((unsigned)ry >= (unsigned)HH) continue;   // wave-uniform

        f32x4 accG[4][4];
#pragma unroll
        for (int fm = 0; fm < 4; ++fm) {
            float bv[4];
#pragma unroll
            for (int j = 0; j < 4; ++j)
                bv[j] = b12[(wm * 64 + fm * 16 + kg * 4 + j) * 9 + tap];
#pragma unroll
            for (int fn = 0; fn < 4; ++fn)
#pragma unroll
                for (int j = 0; j < 4; ++j) accG[fm][fn][j] = bv[j];
        }

#pragma unroll
        for (int ks = 0; ks < 4; ++ks) {
            bf16x8 bC[4];
#pragma unroll
            for (int f = 0; f < 4; ++f) {
                const int px = wn * 64 + f * 16 + l15;
                bC[f] = *(const bf16x8*)(smem +
                    swz((u32)(px * 256 + ks * 64 + kg * 16)));
            }
#pragma unroll
            for (int fm = 0; fm < 4; ++fm) {
                const size_t ao = ((size_t)(tap * 128 + wm * 64 + fm * 16 + l15)) * 128
                                  + ks * 32 + kg * 8;
                const bf16x8 ah = *(const bf16x8*)(w12p + ao);
                const bf16x8 al = *(const bf16x8*)(w12p + 147456 + ao);
#pragma unroll
                for (int fn = 0; fn < 4; ++fn) {
                    accG[fm][fn] = __builtin_amdgcn_mfma_f32_16x16x32_bf16(
                        al, bC[fn], accG[fm][fn], 0, 0, 0);
                    accG[fm][fn] = __builtin_amdgcn_mfma_f32_16x16x32_bf16(
                        ah, bC[fn], accG[fm][fn], 0, 0, 0);
                }
            }
        }

        // fold: accL += G_k * x[ci][ry][px+dxo]
#pragma unroll
        for (int fm = 0; fm < 4; ++fm)
#pragma unroll
            for (int fn = 0; fn < 4; ++fn) {
                const int px = wn * 64 + fn * 16 + l15;
                const int rx = px + dxo;
                const bool okx = (unsigned)rx < (unsigned)WW;
                const float* xr = xb + (size_t)ry * WW + (okx ? rx : 0);
#pragma unroll
                for (int j = 0; j < 4; ++j) {
                    const int ci = wm * 64 + fm * 16 + kg * 4 + j;
                    const float xv = okx ? xr[(size_t)ci * PP] : 0.0f;
                    accL[fm][fn][j] = fmaf(accG[fm][fn][j], xv, accL[fm][fn][j]);
                }
            }
    }

    __syncthreads();
    u16* img = (u16*)smem;
#pragma unroll
    for (int fm = 0; fm < 4; ++fm) {
        float sc[4], sh[4];
#pragma unroll
        for (int j = 0; j < 4; ++j) {
            const int cc = wm * 64 + fm * 16 + kg * 4 + j;
            sc[j] = g1[cc] * rsqrtf(v1[cc] + EPSN);
            sh[j] = be1[cc] - m1[cc] * sc[j];
        }
#pragma unroll
        for (int fn = 0; fn < 4; ++fn) {
            const int px = wn * 64 + fn * 16 + l15;
            const int c0 = wm * 64 + fm * 16 + kg * 4;
            u16 hh[4];
#pragma unroll
            for (int j = 0; j < 4; ++j)
                hh[j] = f2bf(fmaxf(fmaf(accL[fm][fn][j], sc[j], sh[j]), 0.0f));
            const u32 off = swz((u32)(px * 256 + c0 * 2));
            uint2 vh;
            vh.x = (u32)hh[0] | ((u32)hh[1] << 16);
            vh.y = (u32)hh[2] | ((u32)hh[3] << 16);
            *(uint2*)((char*)img + off) = vh;
        }
    }
    __syncthreads();
    uint4* gd = (uint4*)(locp + ((size_t)b * 128 + y) * 16384);
    const uint4* s4 = (const uint4*)smem;
    for (int i = t; i < 2048; i += 256) gd[i] = s4[i];
}

// ---------------------------------------------------------------------------
// K5: channel-mix bmm via MFMA (2-pass) + BN2 + ReLU -> xpad3 interior
// ---------------------------------------------------------------------------
__global__ __launch_bounds__(256, 2) void k_bmm_mfma(
    const u16* __restrict__ locp, const u16* __restrict__ w22p,
    const float* __restrict__ g2, const float* __restrict__ be2,
    const float* __restrict__ m2, const float* __restrict__ v2,
    u16* __restrict__ x3)
{
    __shared__ char smem[32768];
    const int t = threadIdx.x;
    const int wave = t >> 6, lane = t & 63;
    const int wm = wave >> 1, wn = wave & 1;
    const int l15 = lane & 15, kg = lane >> 4;
    const int y = blockIdx.x, b = blockIdx.y;

    {
        const u16* gb = locp + ((size_t)b * 128 + y) * 16384;
        for (int iss = wave; iss < 32; iss += 4)
            gld_lds16((const char*)gb + iss * 1024 + lane * 16,
                      smem + iss * 1024);
    }
    asm volatile("s_waitcnt vmcnt(0)" ::: "memory");
    __syncthreads();

    f32x4 acc[4][4];
#pragma unroll
    for (int fm = 0; fm < 4; ++fm)
#pragma unroll
        for (int fn = 0; fn < 4; ++fn)
#pragma unroll
            for (int j = 0; j < 4; ++j) acc[fm][fn][j] = 0.0f;

#pragma unroll
    for (int ks = 0; ks < 4; ++ks) {
        bf16x8 bC[4];
#pragma unroll
        for (int f = 0; f < 4; ++f) {
            const int px = wn * 64 + f * 16 + l15;
            bC[f] = *(const bf16x8*)(smem +
                swz((u32)(px * 256 + ks * 64 + kg * 16)));
        }
#pragma unroll
        for (int fm = 0; fm < 4; ++fm) {
            const size_t ao = ((size_t)(b * 128 + wm * 64 + fm * 16 + l15)) * 128
                              + ks * 32 + kg * 8;
            const bf16x8 ah = *(const bf16x8*)(w22p + ao);
            const bf16x8 al = *(const bf16x8*)(w22p + 65536 + ao);
#pragma unroll
            for (int fn = 0; fn < 4; ++fn) {
                acc[fm][fn] = __builtin_amdgcn_mfma_f32_16x16x32_bf16(
                    al, bC[fn], acc[fm][fn], 0, 0, 0);
                acc[fm][fn] = __builtin_amdgcn_mfma_f32_16x16x32_bf16(
                    ah, bC[fn], acc[fm][fn], 0, 0, 0);
            }
        }
    }

    __syncthreads();
    u16* img = (u16*)smem;   // LINEAR [px][c] for conv3 staging
#pragma unroll
    for (int fm = 0; fm < 4; ++fm) {
        float sc[4], sh[4];
#pragma unroll
        for (int j = 0; j < 4; ++j) {
            const int cc = wm * 64 + fm * 16 + kg * 4 + j;
            sc[j] = g2[cc] * rsqrtf(v2[cc] + EPSN);
            sh[j] = be2[cc] - m2[cc] * sc[j];
        }
#pragma unroll
        for (int fn = 0; fn < 4; ++fn) {
            const int px = wn * 64 + fn * 16 + l15;
            const int c0 = wm * 64 + fm * 16 + kg * 4;
            u16 hh[4];
#pragma unroll
            for (int j = 0; j < 4; ++j)
                hh[j] = f2bf(fmaxf(fmaf(acc[fm][fn][j], sc[j], sh[j]), 0.0f));
            const u32 off = (u32)(px * 256 + c0 * 2);
            uint2 vh;
            vh.x = (u32)hh[0] | ((u32)hh[1] << 16);
            vh.y = (u32)hh[2] | ((u32)hh[3] << 16);
            *(uint2*)((char*)img + off) = vh;
        }
    }
    __syncthreads();
    uint4* gd = (uint4*)(x3 + (((size_t)b * 130 + y + 1) * 130 + 1) * 128);
    const uint4* s4 = (const uint4*)smem;
    for (int i = t; i < 2048; i += 256) gd[i] = s4[i];
}

// ---------------------------------------------------------------------------
// K5b: zero the halo borders of xpad3 (single buffer).
// ---------------------------------------------------------------------------
__global__ __launch_bounds__(256) void k_zero3(u16* __restrict__ x3)
{
    const int idx = blockIdx.x * 256 + threadIdx.x;
    if (idx >= 132096) return;                    // 4 batches x 33024 u32
    const int b = idx / 33024;
    int r2 = idx % 33024;
    u32* base = (u32*)(x3 + (size_t)b * 2163200);
    if (r2 < 8320)            base[r2] = 0u;                               // row 0
    else if (r2 < 16640)      base[(size_t)129 * 8320 + (r2 - 8320)] = 0u; // row 129
    else {
        const int q = r2 - 16640;                 // 128 rows x 2 sides x 64 u32
        const int w = q & 63;
        const int r = q >> 6;
        const int row = 1 + (r >> 1);
        const int side = r & 1;
        base[(size_t)row * 8320 + (side ? 8256 : 0) + w] = 0u;
    }
}

// ---------------------------------------------------------------------------
extern "C" void kernel_launch(void* const* d_in, const int* in_sizes, int n_in,
                              void* d_out, int out_size, void* d_ws, size_t ws_size,
                              hipStream_t stream)
{
    (void)in_sizes; (void)n_in; (void)out_size; (void)ws_size;

    const float* input  = (const float*)d_in[0];
    const float* weight = (const float*)d_in[1];
    const float* w11    = (const float*)d_in[2];
    const float* b11    = (const float*)d_in[3];
    const float* w12    = (const float*)d_in[4];
    const float* b12    = (const float*)d_in[5];
    const float* w21    = (const float*)d_in[6];
    const float* b21    = (const float*)d_in[7];
    const float* w22    = (const float*)d_in[8];
    const float* b22    = (const float*)d_in[9];
    const float* g1     = (const float*)d_in[10];
    const float* be1    = (const float*)d_in[11];
    const float* m1     = (const float*)d_in[12];
    const float* v1     = (const float*)d_in[13];
    const float* g2     = (const float*)d_in[14];
    const float* be2    = (const float*)d_in[15];
    const float* m2     = (const float*)d_in[16];
    const float* v2     = (const float*)d_in[17];
    const float* w3     = (const float*)d_in[18];
    const float* g3     = (const float*)d_in[19];
    const float* be3    = (const float*)d_in[20];
    const float* m3     = (const float*)d_in[21];
    const float* v3     = (const float*)d_in[22];

    // Workspace (float offsets), total ~80MB:
    //  y2o 0 (+8388608) | pooled 8388608 (+512) | w22p 8389120 (+65536)
    //  wAd 8454656 (+442368) | wA3 8897024 (+147456) | w12p 9044480 (+147456)
    //  G 9191936 (+6489600): xpadD (dead after conv_dual) / locp alias
    //  H 15681536 (+4326400): y1img (dead after guided) / x3 alias
    float* ws     = (float*)d_ws;
    float* y2o    = ws;
    float* pooled = ws + 8388608;
    u16*   w22p   = (u16*)(ws + 8389120);
    u16*   wAd    = (u16*)(ws + 8454656);
    u16*   wA3    = (u16*)(ws + 8897024);
    u16*   w12p   = (u16*)(ws + 9044480);
    u16*   xpadD  = (u16*)(ws + 9191936);      // 12979200 u16
    u16*   locp   = (u16*)(ws + 9191936);      // aliases xpadD (dead)
    u16*   y1img  = (u16*)(ws + 15681536);     // 8388608 u16
    u16*   x3     = (u16*)(ws + 15681536);     // aliases y1img (dead)
    float* outp   = (float*)d_out;

    k_pack<<<dim3(130, BB), 256, 0, stream>>>(input, CI, weight, CG, xpadD, CIN);
    k_wpack<<<dim3(216), 256, 0, stream>>>(w11, w21, wAd, 2, 6, CIN);
    k_wpack<<<dim3(72), 256, 0, stream>>>(w3, w3, wA3, 1, 4, CI);
    k_wpack12<<<dim3(72), 256, 0, stream>>>(w12, w12p);

    k_conv_mfma<6, true><<<dim3(128, 2, BB), 256, 0, stream>>>(
        xpadD, wAd, b11, b21, nullptr, nullptr, nullptr, nullptr,
        y2o, nullptr, y1img);

    k_pool<<<dim3(CI, BB), 256, 0, stream>>>(y2o, pooled);
    k_w22<<<dim3(64, BB), 256, 0, stream>>>(w22, b22, pooled, w22p);

    k_guided_mfma<<<dim3(128, BB), 256, 0, stream>>>(
        input, y1img, w12p, b12, g1, be1, m1, v1, locp);

    k_zero3<<<dim3(516), 256, 0, stream>>>(x3);

    k_bmm_mfma<<<dim3(128, BB), 256, 0, stream>>>(
        locp, w22p, g2, be2, m2, v2, x3);

    k_conv_mfma<4, false><<<dim3(128, 1, BB), 256, 0, stream>>>(
        x3, wA3, nullptr, nullptr, g3, be3, m3, v3, nullptr, outp, nullptr);
}

// Round 10
// 511.860 us; speedup vs baseline: 1.2834x; 1.2834x over previous
//
#include <hip/hip_runtime.h>
#include <math.h>

// Problem constants (B=4, Ci=128, Cg=64, H=W=128), all fp32.
#define BB   4
#define CI   128
#define CG   64
#define CIN  192
#define HH   128
#define WW   128
#define PP   16384
#define EPSN 1e-5f

typedef unsigned short u16;
typedef unsigned int   u32;
typedef __attribute__((ext_vector_type(8))) short bf16x8;
typedef __attribute__((ext_vector_type(4))) float f32x4;

__device__ __forceinline__ u16 f2bf(float x) {
    union { float f; u32 u; } a; a.f = x;
    u32 u = a.u;
    return (u16)((u + 0x7FFFu + ((u >> 16) & 1u)) >> 16);   // RNE
}
__device__ __forceinline__ float bf2f(u16 h) {
    union { u32 u; float f; } a; a.u = ((u32)h) << 16; return a.f;
}
// XOR-swizzle for [px][c] bf16 row-images (256B per px row).
__device__ __forceinline__ u32 swz(u32 o) { return o ^ ((o >> 4) & 0x70u); }
// Xs slot swizzle: slot s in [0,4) within a 64B channel-row cc.
__device__ __forceinline__ int xslot(int cc) { return (cc >> 1) & 3; }

__device__ __forceinline__ void gld_lds16(const void* g, void* l) {
    __builtin_amdgcn_global_load_lds(
        (const __attribute__((address_space(1))) void*)g,
        (__attribute__((address_space(3))) void*)l, 16, 0, 0);
}
// XCD-aware block->row swizzle for grid.x == 128 (bijective).
__device__ __forceinline__ int yswz(int bid) {
    return ((bid & 7) << 4) | (bid >> 3);
}

// ---------------------------------------------------------------------------
// P1: pad(1) + NCHW->NHWC transpose + RNE bf16 (single image).
// ---------------------------------------------------------------------------
__global__ __launch_bounds__(256) void k_pack(
    const float* __restrict__ src0, int nch0,
    const float* __restrict__ src1, int nch1,
    u16* __restrict__ dst, int cinp)
{
    const int rr = blockIdx.x;   // 0..129
    const int b  = blockIdx.y;
    const int t  = threadIdx.x;
    u16* rh = dst + ((size_t)b * 130 + rr) * 130 * cinp;

    if (rr == 0 || rr == 129) {
        u32* rh4 = (u32*)rh;
        const int tot = 130 * cinp / 2;
        for (int i = t; i < tot; i += 256) rh4[i] = 0u;
        return;
    }
    const int y = rr - 1;
    for (int i = t; i < cinp; i += 256) {
        rh[i] = 0;
        rh[129 * cinp + i] = 0;
    }

    __shared__ float xs[32][129];
    for (int ck = 0; ck < cinp / 32; ++ck) {
        __syncthreads();
        for (int i = t; i < 32 * 128; i += 256) {
            const int ch = i >> 7, col = i & 127;
            const int c = ck * 32 + ch;
            const float* sp = (c < nch0)
                ? src0 + ((size_t)b * nch0 + c) * PP
                : src1 + ((size_t)b * nch1 + (c - nch0)) * PP;
            xs[ch][col] = sp[y * WW + col];
        }
        __syncthreads();
        for (int i = t; i < 512; i += 256) {
            const int col = i >> 2, oct = i & 3;
            u16 hh[8];
#pragma unroll
            for (int j = 0; j < 8; ++j) hh[j] = f2bf(xs[oct * 8 + j][col]);
            const size_t off = (size_t)(col + 1) * cinp + ck * 32 + oct * 8;
            uint4 vh;
            vh.x = (u32)hh[0] | ((u32)hh[1] << 16); vh.y = (u32)hh[2] | ((u32)hh[3] << 16);
            vh.z = (u32)hh[4] | ((u32)hh[5] << 16); vh.w = (u32)hh[6] | ((u32)hh[7] << 16);
            *(uint4*)(rh + off) = vh;
        }
    }
}

// ---------------------------------------------------------------------------
// P2: 3x3 weight rearrange + hi/lo split. dst[half][mb][ck][tap][oc][kk32].
// ---------------------------------------------------------------------------
__global__ __launch_bounds__(256) void k_wpack(
    const float* __restrict__ w0, const float* __restrict__ w1,
    u16* __restrict__ dst, int nmb, int nck, int cin)
{
    const int total = nmb * nck * 9 * 128 * 4;
    const int idx = blockIdx.x * 256 + threadIdx.x;
    if (idx >= total) return;
    const int oct = idx & 3; int r2 = idx >> 2;
    const int oc = r2 & 127; r2 >>= 7;
    const int tap = r2 % 9; r2 /= 9;
    const int ck = r2 % nck; r2 /= nck;
    const int mb = r2;
    const float* w = mb ? w1 : w0;
    u16 hh[8], ll[8];
#pragma unroll
    for (int j = 0; j < 8; ++j) {
        const int c = ck * 32 + oct * 8 + j;
        const float v = w[((size_t)oc * cin + c) * 9 + tap];
        const u16 h = f2bf(v);
        hh[j] = h; ll[j] = f2bf(v - bf2f(h));
    }
    const size_t halfs = (size_t)nmb * nck * 9 * 128 * 32;
    const size_t base = ((((size_t)mb * nck + ck) * 9 + tap) * 128 + oc) * 32 + oct * 8;
    uint4 vh, vl;
    vh.x = (u32)hh[0] | ((u32)hh[1] << 16); vh.y = (u32)hh[2] | ((u32)hh[3] << 16);
    vh.z = (u32)hh[4] | ((u32)hh[5] << 16); vh.w = (u32)hh[6] | ((u32)hh[7] << 16);
    vl.x = (u32)ll[0] | ((u32)ll[1] << 16); vl.y = (u32)ll[2] | ((u32)ll[3] << 16);
    vl.z = (u32)ll[4] | ((u32)ll[5] << 16); vl.w = (u32)ll[6] | ((u32)ll[7] << 16);
    *(uint4*)(dst + base) = vh;
    *(uint4*)(dst + halfs + base) = vl;
}

// ---------------------------------------------------------------------------
// P4: w12 -> w12p[half][tap][cc][c] split bf16.
// ---------------------------------------------------------------------------
__global__ __launch_bounds__(256) void k_wpack12(
    const float* __restrict__ w12, u16* __restrict__ dst)
{
    const int idx = blockIdx.x * 256 + threadIdx.x;   // 18432
    if (idx >= 18432) return;
    const int oct = idx & 15;
    const int g   = idx >> 4;
    const int cc  = g / 9, tap = g % 9;
    u16 hh[8], ll[8];
#pragma unroll
    for (int j = 0; j < 8; ++j) {
        const float v = w12[(size_t)g * 128 + oct * 8 + j];
        const u16 h = f2bf(v);
        hh[j] = h; ll[j] = f2bf(v - bf2f(h));
    }
    const size_t base = ((size_t)(tap * 128 + cc)) * 128 + oct * 8;
    uint4 vh, vl;
    vh.x = (u32)hh[0] | ((u32)hh[1] << 16); vh.y = (u32)hh[2] | ((u32)hh[3] << 16);
    vh.z = (u32)hh[4] | ((u32)hh[5] << 16); vh.w = (u32)hh[6] | ((u32)hh[7] << 16);
    vl.x = (u32)ll[0] | ((u32)ll[1] << 16); vl.y = (u32)ll[2] | ((u32)ll[3] << 16);
    vl.z = (u32)ll[4] | ((u32)ll[5] << 16); vl.w = (u32)ll[6] | ((u32)ll[7] << 16);
    *(uint4*)(dst + base) = vh;
    *(uint4*)(dst + 147456 + base) = vl;
}

// ---------------------------------------------------------------------------
// 3x3 conv implicit-GEMM MFMA, 2-pass (A split hi/lo, B plain bf16).
// r7-proven schedule: per-ck stage + vmcnt(0) + syncthreads, per-tap loads
// left to the compiler. Single-image X, xslot swizzle, XCD y-swizzle.
// ---------------------------------------------------------------------------
template<int NCK, bool DUAL>
__global__ __launch_bounds__(256, 2) void k_conv_mfma(
    const u16* __restrict__ xin, const u16* __restrict__ wA,
    const float* __restrict__ bias0, const float* __restrict__ bias1,
    const float* __restrict__ bng, const float* __restrict__ bnb,
    const float* __restrict__ bnm, const float* __restrict__ bnv,
    float* __restrict__ dstf, float* __restrict__ bnout,
    u16* __restrict__ y1img)
{
    constexpr int CINP = NCK * 32;
    constexpr size_t WHALF = (size_t)(DUAL ? 2 : 1) * NCK * 9 * 128 * 32;

    __shared__ char smem[32768];   // X: 3 rows x 144cc x 32ch x 2B = 27648B

    const int t    = threadIdx.x;
    const int wave = t >> 6;
    const int lane = t & 63;
    const int wm   = wave >> 1, wn = wave & 1;
    const int y    = yswz(blockIdx.x);
    const int mb   = blockIdx.y;
    const int b    = blockIdx.z;
    const int l15  = lane & 15;
    const int kg   = lane >> 4;

    f32x4 acc[4][4];
    if (DUAL) {
        const float* bp = mb ? bias1 : bias0;
#pragma unroll
        for (int fm = 0; fm < 4; ++fm) {
            const int ocb = wm * 64 + fm * 16 + kg * 4;
#pragma unroll
            for (int j = 0; j < 4; ++j) {
                const float bv = bp[ocb + j];
#pragma unroll
                for (int fn = 0; fn < 4; ++fn) acc[fm][fn][j] = bv;
            }
        }
    } else {
#pragma unroll
        for (int fm = 0; fm < 4; ++fm)
#pragma unroll
            for (int fn = 0; fn < 4; ++fn)
#pragma unroll
                for (int j = 0; j < 4; ++j) acc[fm][fn][j] = 0.0f;
    }

    const size_t xrow = (size_t)130 * CINP;

    for (int ck = 0; ck < NCK; ++ck) {
        __syncthreads();   // prev chunk's LDS reads complete
        // ---- stage X chunk: 27 x 1KB, pre-swizzled source -> linear LDS ----
        for (int idx = wave; idx < 27; idx += 4) {
            const int r = idx / 9, iss = idx % 9;
            const u16* gb = xin + ((size_t)b * 130 + (y + r)) * xrow + ck * 32;
            const int cc = iss * 16 + (lane >> 2);
            const int rb = ((lane & 3) << 4) ^ (xslot(cc) << 4);
            gld_lds16((const char*)gb + (size_t)cc * (CINP * 2) + rb,
                      smem + r * 9216 + iss * 1024);
        }
        asm volatile("s_waitcnt vmcnt(0)" ::: "memory");
        __syncthreads();

        for (int tap = 0; tap < 9; ++tap) {
            const int dy = tap / 3, dx = tap % 3;
            const size_t abase = (((size_t)mb * NCK + ck) * 9 + tap) * 4096;
            bf16x8 ah[4], al[4], bC[4];
#pragma unroll
            for (int f = 0; f < 4; ++f) {
                const size_t ao = abase + (size_t)(wm * 64 + f * 16 + l15) * 32 + kg * 8;
                ah[f] = *(const bf16x8*)(wA + ao);
                al[f] = *(const bf16x8*)(wA + WHALF + ao);
                const int cc = wn * 64 + f * 16 + l15 + dx;
                bC[f] = *(const bf16x8*)(smem + dy * 9216 + cc * 64
                                         + ((kg ^ xslot(cc)) << 4));
            }
#pragma unroll
            for (int fm = 0; fm < 4; ++fm)
#pragma unroll
                for (int fn = 0; fn < 4; ++fn) {
                    acc[fm][fn] = __builtin_amdgcn_mfma_f32_16x16x32_bf16(
                        al[fm], bC[fn], acc[fm][fn], 0, 0, 0);
                    acc[fm][fn] = __builtin_amdgcn_mfma_f32_16x16x32_bf16(
                        ah[fm], bC[fn], acc[fm][fn], 0, 0, 0);
                }
        }
    }

    if (DUAL && mb == 0) {
        // y1: ReLU + RNE bf16 swizzled [px][c] image -> coalesced 32KB store
        __syncthreads();
        u16* img = (u16*)smem;
#pragma unroll
        for (int fm = 0; fm < 4; ++fm)
#pragma unroll
            for (int fn = 0; fn < 4; ++fn) {
                const int px = wn * 64 + fn * 16 + l15;
                const int c0 = wm * 64 + fm * 16 + kg * 4;
                u16 hh[4];
#pragma unroll
                for (int j = 0; j < 4; ++j)
                    hh[j] = f2bf(fmaxf(acc[fm][fn][j], 0.0f));
                const u32 off = swz((u32)(px * 256 + c0 * 2));
                uint2 vh;
                vh.x = (u32)hh[0] | ((u32)hh[1] << 16);
                vh.y = (u32)hh[2] | ((u32)hh[3] << 16);
                *(uint2*)((char*)img + off) = vh;
            }
        __syncthreads();
        uint4* gd = (uint4*)(y1img + ((size_t)b * 128 + y) * 16384);
        const uint4* s4 = (const uint4*)smem;
        for (int i = t; i < 2048; i += 256) gd[i] = s4[i];
        return;
    }

    // fp32 paths (DUAL mb=1 -> y2o; !DUAL -> BN+ReLU -> out)
    float* dst = DUAL ? dstf : bnout;
#pragma unroll
    for (int fm = 0; fm < 4; ++fm) {
#pragma unroll
        for (int j = 0; j < 4; ++j) {
            const int oc = wm * 64 + fm * 16 + kg * 4 + j;
            float sc = 1.0f, sh = 0.0f;
            if (!DUAL) {
                sc = bng[oc] * rsqrtf(bnv[oc] + EPSN);
                sh = bnb[oc] - bnm[oc] * sc;
            }
            const size_t obase = ((size_t)b * CI + oc) * PP + (size_t)y * WW;
#pragma unroll
            for (int fn = 0; fn < 4; ++fn) {
                const int px = wn * 64 + fn * 16 + l15;
                float v = acc[fm][fn][j];
                if (!DUAL) v = fmaf(v, sc, sh);
                dst[obase + px] = fmaxf(v, 0.0f);
            }
        }
    }
}

// ---------------------------------------------------------------------------
// K2: global average pool of y2 -> pooled[b][c]
// ---------------------------------------------------------------------------
__global__ __launch_bounds__(256) void k_pool(
    const float* __restrict__ y2, float* __restrict__ pooled)
{
    const int c = blockIdx.x, b = blockIdx.y, t = threadIdx.x;
    const float* src = y2 + ((size_t)b * CI + c) * PP;
    float s = 0.0f;
    for (int i = t; i < PP; i += 256) s += src[i];
    __shared__ float red[256];
    red[t] = s;
    __syncthreads();
    for (int st = 128; st > 0; st >>= 1) {
        if (t < st) red[t] += red[t + st];
        __syncthreads();
    }
    if (t == 0) pooled[b * CI + c] = red[0] * (1.0f / PP);
}

// ---------------------------------------------------------------------------
// K3: w22o = w22 . pooled + b22 -> split bf16 [half][b][i][j]
// ---------------------------------------------------------------------------
__global__ __launch_bounds__(256) void k_w22(
    const float* __restrict__ w22, const float* __restrict__ b22,
    const float* __restrict__ pooled, u16* __restrict__ w22p)
{
    const int b = blockIdx.y;
    const int o = blockIdx.x * 256 + threadIdx.x;
    __shared__ float pl[CI];
    if (threadIdx.x < CI) pl[threadIdx.x] = pooled[b * CI + threadIdx.x];
    __syncthreads();
    const float4* wr = (const float4*)(w22 + (size_t)o * CI);
    float acc = b22[o];
#pragma unroll 8
    for (int c4 = 0; c4 < CI / 4; ++c4) {
        const float4 w = wr[c4];
        acc += w.x * pl[c4 * 4 + 0] + w.y * pl[c4 * 4 + 1] +
               w.z * pl[c4 * 4 + 2] + w.w * pl[c4 * 4 + 3];
    }
    const u16 h = f2bf(acc);
    w22p[(size_t)b * 16384 + o] = h;
    w22p[65536 + (size_t)b * 16384 + o] = f2bf(acc - bf2f(h));
}

// ---------------------------------------------------------------------------
// K4: guided conv via MFMA (2-pass), fold with fp32 x, BN1+ReLU -> locp image
// ---------------------------------------------------------------------------
__global__ __launch_bounds__(256, 2) void k_guided_mfma(
    const float* __restrict__ input,
    const u16* __restrict__ y1img,   // [b][y][16384] swz image
    const u16* __restrict__ w12p,    // [half +147456][tap][cc][c]
    const float* __restrict__ b12,
    const float* __restrict__ g1, const float* __restrict__ be1,
    const float* __restrict__ m1, const float* __restrict__ v1,
    u16* __restrict__ locp)          // same image format
{
    __shared__ char smem[32768];
    const int t = threadIdx.x;
    const int wave = t >> 6, lane = t & 63;
    const int wm = wave >> 1, wn = wave & 1;
    const int l15 = lane & 15, kg = lane >> 4;
    const int y = yswz(blockIdx.x), b = blockIdx.y;

    {
        const u16* gb = y1img + ((size_t)b * 128 + y) * 16384;
        for (int iss = wave; iss < 32; iss += 4)
            gld_lds16((const char*)gb + iss * 1024 + lane * 16,
                      smem + iss * 1024);
    }
    asm volatile("s_waitcnt vmcnt(0)" ::: "memory");
    __syncthreads();

    f32x4 accL[4][4];
#pragma unroll
    for (int fm = 0; fm < 4; ++fm)
#pragma unroll
        for (int fn = 0; fn < 4; ++fn)
#pragma unroll
            for (int j = 0; j < 4; ++j) accL[fm][fn][j] = 0.0f;

    const float* xb = input + (size_t)b * CI * PP;

    for (int tap = 0; tap < 9; ++tap) {
        const int ry  = y + tap / 3 - 1;
        const int dxo = tap % 3 - 1;
        if ((unsigned)ry >= (unsigned)HH) continue;   // wave-uniform

        f32x4 accG[4][4];
#pragma unroll
        for (int fm = 0; fm < 4; ++fm) {
            float bv[4];
#pragma unroll
            for (int j = 0; j < 4; ++j)
                bv[j] = b12[(wm * 64 + fm * 16 + kg * 4 + j) * 9 + tap];
#pragma unroll
            for (int fn = 0; fn < 4; ++fn)
#pragma unroll
                for (int j = 0; j < 4; ++j) accG[fm][fn][j] = bv[j];
        }

#pragma unroll
        for (int ks = 0; ks < 4; ++ks) {
            bf16x8 bC[4];
#pragma unroll
            for (int f = 0; f < 4; ++f) {
                const int px = wn * 64 + f * 16 + l15;
                bC[f] = *(const bf16x8*)(smem +
                    swz((u32)(px * 256 + ks * 64 + kg * 16)));
            }
#pragma unroll
            for (int fm = 0; fm < 4; ++fm) {
                const size_t ao = ((size_t)(tap * 128 + wm * 64 + fm * 16 + l15)) * 128
                                  + ks * 32 + kg * 8;
                const bf16x8 ah = *(const bf16x8*)(w12p + ao);
                const bf16x8 al = *(const bf16x8*)(w12p + 147456 + ao);
#pragma unroll
                for (int fn = 0; fn < 4; ++fn) {
                    accG[fm][fn] = __builtin_amdgcn_mfma_f32_16x16x32_bf16(
                        al, bC[fn], accG[fm][fn], 0, 0, 0);
                    accG[fm][fn] = __builtin_amdgcn_mfma_f32_16x16x32_bf16(
                        ah, bC[fn], accG[fm][fn], 0, 0, 0);
                }
            }
        }

        // fold: accL += G_k * x[ci][ry][px+dxo]
#pragma unroll
        for (int fm = 0; fm < 4; ++fm)
#pragma unroll
            for (int fn = 0; fn < 4; ++fn) {
                const int px = wn * 64 + fn * 16 + l15;
                const int rx = px + dxo;
                const bool okx = (unsigned)rx < (unsigned)WW;
                const float* xr = xb + (size_t)ry * WW + (okx ? rx : 0);
#pragma unroll
                for (int j = 0; j < 4; ++j) {
                    const int ci = wm * 64 + fm * 16 + kg * 4 + j;
                    const float xv = okx ? xr[(size_t)ci * PP] : 0.0f;
                    accL[fm][fn][j] = fmaf(accG[fm][fn][j], xv, accL[fm][fn][j]);
                }
            }
    }

    __syncthreads();
    u16* img = (u16*)smem;
#pragma unroll
    for (int fm = 0; fm < 4; ++fm) {
        float sc[4], sh[4];
#pragma unroll
        for (int j = 0; j < 4; ++j) {
            const int cc = wm * 64 + fm * 16 + kg * 4 + j;
            sc[j] = g1[cc] * rsqrtf(v1[cc] + EPSN);
            sh[j] = be1[cc] - m1[cc] * sc[j];
        }
#pragma unroll
        for (int fn = 0; fn < 4; ++fn) {
            const int px = wn * 64 + fn * 16 + l15;
            const int c0 = wm * 64 + fm * 16 + kg * 4;
            u16 hh[4];
#pragma unroll
            for (int j = 0; j < 4; ++j)
                hh[j] = f2bf(fmaxf(fmaf(accL[fm][fn][j], sc[j], sh[j]), 0.0f));
            const u32 off = swz((u32)(px * 256 + c0 * 2));
            uint2 vh;
            vh.x = (u32)hh[0] | ((u32)hh[1] << 16);
            vh.y = (u32)hh[2] | ((u32)hh[3] << 16);
            *(uint2*)((char*)img + off) = vh;
        }
    }
    __syncthreads();
    uint4* gd = (uint4*)(locp + ((size_t)b * 128 + y) * 16384);
    const uint4* s4 = (const uint4*)smem;
    for (int i = t; i < 2048; i += 256) gd[i] = s4[i];
}

// ---------------------------------------------------------------------------
// K5: channel-mix bmm via MFMA (2-pass) + BN2 + ReLU -> xpad3 interior
// ---------------------------------------------------------------------------
__global__ __launch_bounds__(256, 2) void k_bmm_mfma(
    const u16* __restrict__ locp, const u16* __restrict__ w22p,
    const float* __restrict__ g2, const float* __restrict__ be2,
    const float* __restrict__ m2, const float* __restrict__ v2,
    u16* __restrict__ x3)
{
    __shared__ char smem[32768];
    const int t = threadIdx.x;
    const int wave = t >> 6, lane = t & 63;
    const int wm = wave >> 1, wn = wave & 1;
    const int l15 = lane & 15, kg = lane >> 4;
    const int y = blockIdx.x, b = blockIdx.y;

    {
        const u16* gb = locp + ((size_t)b * 128 + y) * 16384;
        for (int iss = wave; iss < 32; iss += 4)
            gld_lds16((const char*)gb + iss * 1024 + lane * 16,
                      smem + iss * 1024);
    }
    asm volatile("s_waitcnt vmcnt(0)" ::: "memory");
    __syncthreads();

    f32x4 acc[4][4];
#pragma unroll
    for (int fm = 0; fm < 4; ++fm)
#pragma unroll
        for (int fn = 0; fn < 4; ++fn)
#pragma unroll
            for (int j = 0; j < 4; ++j) acc[fm][fn][j] = 0.0f;

#pragma unroll
    for (int ks = 0; ks < 4; ++ks) {
        bf16x8 bC[4];
#pragma unroll
        for (int f = 0; f < 4; ++f) {
            const int px = wn * 64 + f * 16 + l15;
            bC[f] = *(const bf16x8*)(smem +
                swz((u32)(px * 256 + ks * 64 + kg * 16)));
        }
#pragma unroll
        for (int fm = 0; fm < 4; ++fm) {
            const size_t ao = ((size_t)(b * 128 + wm * 64 + fm * 16 + l15)) * 128
                              + ks * 32 + kg * 8;
            const bf16x8 ah = *(const bf16x8*)(w22p + ao);
            const bf16x8 al = *(const bf16x8*)(w22p + 65536 + ao);
#pragma unroll
            for (int fn = 0; fn < 4; ++fn) {
                acc[fm][fn] = __builtin_amdgcn_mfma_f32_16x16x32_bf16(
                    al, bC[fn], acc[fm][fn], 0, 0, 0);
                acc[fm][fn] = __builtin_amdgcn_mfma_f32_16x16x32_bf16(
                    ah, bC[fn], acc[fm][fn], 0, 0, 0);
            }
        }
    }

    __syncthreads();
    u16* img = (u16*)smem;   // LINEAR [px][c] for conv3 staging
#pragma unroll
    for (int fm = 0; fm < 4; ++fm) {
        float sc[4], sh[4];
#pragma unroll
        for (int j = 0; j < 4; ++j) {
            const int cc = wm * 64 + fm * 16 + kg * 4 + j;
            sc[j] = g2[cc] * rsqrtf(v2[cc] + EPSN);
            sh[j] = be2[cc] - m2[cc] * sc[j];
        }
#pragma unroll
        for (int fn = 0; fn < 4; ++fn) {
            const int px = wn * 64 + fn * 16 + l15;
            const int c0 = wm * 64 + fm * 16 + kg * 4;
            u16 hh[4];
#pragma unroll
            for (int j = 0; j < 4; ++j)
                hh[j] = f2bf(fmaxf(fmaf(acc[fm][fn][j], sc[j], sh[j]), 0.0f));
            const u32 off = (u32)(px * 256 + c0 * 2);
            uint2 vh;
            vh.x = (u32)hh[0] | ((u32)hh[1] << 16);
            vh.y = (u32)hh[2] | ((u32)hh[3] << 16);
            *(uint2*)((char*)img + off) = vh;
        }
    }
    __syncthreads();
    uint4* gd = (uint4*)(x3 + (((size_t)b * 130 + y + 1) * 130 + 1) * 128);
    const uint4* s4 = (const uint4*)smem;
    for (int i = t; i < 2048; i += 256) gd[i] = s4[i];
}

// ---------------------------------------------------------------------------
// K5b: zero the halo borders of xpad3 (single buffer).
// ---------------------------------------------------------------------------
__global__ __launch_bounds__(256) void k_zero3(u16* __restrict__ x3)
{
    const int idx = blockIdx.x * 256 + threadIdx.x;
    if (idx >= 132096) return;                    // 4 batches x 33024 u32
    const int b = idx / 33024;
    int r2 = idx % 33024;
    u32* base = (u32*)(x3 + (size_t)b * 2163200);
    if (r2 < 8320)            base[r2] = 0u;                               // row 0
    else if (r2 < 16640)      base[(size_t)129 * 8320 + (r2 - 8320)] = 0u; // row 129
    else {
        const int q = r2 - 16640;                 // 128 rows x 2 sides x 64 u32
        const int w = q & 63;
        const int r = q >> 6;
        const int row = 1 + (r >> 1);
        const int side = r & 1;
        base[(size_t)row * 8320 + (side ? 8256 : 0) + w] = 0u;
    }
}

// ---------------------------------------------------------------------------
extern "C" void kernel_launch(void* const* d_in, const int* in_sizes, int n_in,
                              void* d_out, int out_size, void* d_ws, size_t ws_size,
                              hipStream_t stream)
{
    (void)in_sizes; (void)n_in; (void)out_size; (void)ws_size;

    const float* input  = (const float*)d_in[0];
    const float* weight = (const float*)d_in[1];
    const float* w11    = (const float*)d_in[2];
    const float* b11    = (const float*)d_in[3];
    const float* w12    = (const float*)d_in[4];
    const float* b12    = (const float*)d_in[5];
    const float* w21    = (const float*)d_in[6];
    const float* b21    = (const float*)d_in[7];
    const float* w22    = (const float*)d_in[8];
    const float* b22    = (const float*)d_in[9];
    const float* g1     = (const float*)d_in[10];
    const float* be1    = (const float*)d_in[11];
    const float* m1     = (const float*)d_in[12];
    const float* v1     = (const float*)d_in[13];
    const float* g2     = (const float*)d_in[14];
    const float* be2    = (const float*)d_in[15];
    const float* m2     = (const float*)d_in[16];
    const float* v2     = (const float*)d_in[17];
    const float* w3     = (const float*)d_in[18];
    const float* g3     = (const float*)d_in[19];
    const float* be3    = (const float*)d_in[20];
    const float* m3     = (const float*)d_in[21];
    const float* v3     = (const float*)d_in[22];

    // Workspace (float offsets), total ~80MB:
    //  y2o 0 (+8388608) | pooled 8388608 (+512) | w22p 8389120 (+65536)
    //  wAd 8454656 (+442368) | wA3 8897024 (+147456) | w12p 9044480 (+147456)
    //  G 9191936 (+6489600): xpadD (dead after conv_dual) / locp alias
    //  H 15681536 (+4326400): y1img (dead after guided) / x3 alias
    float* ws     = (float*)d_ws;
    float* y2o    = ws;
    float* pooled = ws + 8388608;
    u16*   w22p   = (u16*)(ws + 8389120);
    u16*   wAd    = (u16*)(ws + 8454656);
    u16*   wA3    = (u16*)(ws + 8897024);
    u16*   w12p   = (u16*)(ws + 9044480);
    u16*   xpadD  = (u16*)(ws + 9191936);      // 12979200 u16
    u16*   locp   = (u16*)(ws + 9191936);      // aliases xpadD (dead)
    u16*   y1img  = (u16*)(ws + 15681536);     // 8388608 u16
    u16*   x3     = (u16*)(ws + 15681536);     // aliases y1img (dead)
    float* outp   = (float*)d_out;

    k_pack<<<dim3(130, BB), 256, 0, stream>>>(input, CI, weight, CG, xpadD, CIN);
    k_wpack<<<dim3(216), 256, 0, stream>>>(w11, w21, wAd, 2, 6, CIN);
    k_wpack<<<dim3(72), 256, 0, stream>>>(w3, w3, wA3, 1, 4, CI);
    k_wpack12<<<dim3(72), 256, 0, stream>>>(w12, w12p);

    k_conv_mfma<6, true><<<dim3(128, 2, BB), 256, 0, stream>>>(
        xpadD, wAd, b11, b21, nullptr, nullptr, nullptr, nullptr,
        y2o, nullptr, y1img);

    k_pool<<<dim3(CI, BB), 256, 0, stream>>>(y2o, pooled);
    k_w22<<<dim3(64, BB), 256, 0, stream>>>(w22, b22, pooled, w22p);

    k_guided_mfma<<<dim3(128, BB), 256, 0, stream>>>(
        input, y1img, w12p, b12, g1, be1, m1, v1, locp);

    k_zero3<<<dim3(516), 256, 0, stream>>>(x3);

    k_bmm_mfma<<<dim3(128, BB), 256, 0, stream>>>(
        locp, w22p, g2, be2, m2, v2, x3);

    k_conv_mfma<4, false><<<dim3(128, 1, BB), 256, 0, stream>>>(
        x3, wA3, nullptr, nullptr, g3, be3, m3, v3, nullptr, outp, nullptr);
}

// Round 11
// 483.404 us; speedup vs baseline: 1.3589x; 1.0589x over previous
//
#include <hip/hip_runtime.h>
#include <math.h>

// Problem constants (B=4, Ci=128, Cg=64, H=W=128), all fp32.
#define BB   4
#define CI   128
#define CG   64
#define CIN  192
#define HH   128
#define WW   128
#define PP   16384
#define EPSN 1e-5f

typedef unsigned short u16;
typedef unsigned int   u32;
typedef __attribute__((ext_vector_type(8))) short bf16x8;
typedef __attribute__((ext_vector_type(4))) float f32x4;

__device__ __forceinline__ u16 f2bf(float x) {
    union { float f; u32 u; } a; a.f = x;
    u32 u = a.u;
    return (u16)((u + 0x7FFFu + ((u >> 16) & 1u)) >> 16);   // RNE
}
__device__ __forceinline__ float bf2f(u16 h) {
    union { u32 u; float f; } a; a.u = ((u32)h) << 16; return a.f;
}
// XOR-swizzle for [px][c] bf16 row-images (256B per px row).
__device__ __forceinline__ u32 swz(u32 o) { return o ^ ((o >> 4) & 0x70u); }
// Xs slot swizzle: slot s in [0,4) within a 64B channel-row cc.
__device__ __forceinline__ int xslot(int cc) { return (cc >> 1) & 3; }

__device__ __forceinline__ void gld_lds16(const void* g, void* l) {
    __builtin_amdgcn_global_load_lds(
        (const __attribute__((address_space(1))) void*)g,
        (__attribute__((address_space(3))) void*)l, 16, 0, 0);
}
// XCD-aware block->row swizzle for grid.x == 128 (bijective).
__device__ __forceinline__ int yswz(int bid) {
    return ((bid & 7) << 4) | (bid >> 3);
}

// ---------------------------------------------------------------------------
// P1: pad(1) + NCHW->NHWC transpose + RNE bf16 (single image).
// ---------------------------------------------------------------------------
__global__ __launch_bounds__(256) void k_pack(
    const float* __restrict__ src0, int nch0,
    const float* __restrict__ src1, int nch1,
    u16* __restrict__ dst, int cinp)
{
    const int rr = blockIdx.x;   // 0..129
    const int b  = blockIdx.y;
    const int t  = threadIdx.x;
    u16* rh = dst + ((size_t)b * 130 + rr) * 130 * cinp;

    if (rr == 0 || rr == 129) {
        u32* rh4 = (u32*)rh;
        const int tot = 130 * cinp / 2;
        for (int i = t; i < tot; i += 256) rh4[i] = 0u;
        return;
    }
    const int y = rr - 1;
    for (int i = t; i < cinp; i += 256) {
        rh[i] = 0;
        rh[129 * cinp + i] = 0;
    }

    __shared__ float xs[32][129];
    for (int ck = 0; ck < cinp / 32; ++ck) {
        __syncthreads();
        for (int i = t; i < 32 * 128; i += 256) {
            const int ch = i >> 7, col = i & 127;
            const int c = ck * 32 + ch;
            const float* sp = (c < nch0)
                ? src0 + ((size_t)b * nch0 + c) * PP
                : src1 + ((size_t)b * nch1 + (c - nch0)) * PP;
            xs[ch][col] = sp[y * WW + col];
        }
        __syncthreads();
        for (int i = t; i < 512; i += 256) {
            const int col = i >> 2, oct = i & 3;
            u16 hh[8];
#pragma unroll
            for (int j = 0; j < 8; ++j) hh[j] = f2bf(xs[oct * 8 + j][col]);
            const size_t off = (size_t)(col + 1) * cinp + ck * 32 + oct * 8;
            uint4 vh;
            vh.x = (u32)hh[0] | ((u32)hh[1] << 16); vh.y = (u32)hh[2] | ((u32)hh[3] << 16);
            vh.z = (u32)hh[4] | ((u32)hh[5] << 16); vh.w = (u32)hh[6] | ((u32)hh[7] << 16);
            *(uint4*)(rh + off) = vh;
        }
    }
}

// ---------------------------------------------------------------------------
// P2: 3x3 weight rearrange + hi/lo split. dst[half][mb][ck][tap][oc][kk32].
// ---------------------------------------------------------------------------
__global__ __launch_bounds__(256) void k_wpack(
    const float* __restrict__ w0, const float* __restrict__ w1,
    u16* __restrict__ dst, int nmb, int nck, int cin)
{
    const int total = nmb * nck * 9 * 128 * 4;
    const int idx = blockIdx.x * 256 + threadIdx.x;
    if (idx >= total) return;
    const int oct = idx & 3; int r2 = idx >> 2;
    const int oc = r2 & 127; r2 >>= 7;
    const int tap = r2 % 9; r2 /= 9;
    const int ck = r2 % nck; r2 /= nck;
    const int mb = r2;
    const float* w = mb ? w1 : w0;
    u16 hh[8], ll[8];
#pragma unroll
    for (int j = 0; j < 8; ++j) {
        const int c = ck * 32 + oct * 8 + j;
        const float v = w[((size_t)oc * cin + c) * 9 + tap];
        const u16 h = f2bf(v);
        hh[j] = h; ll[j] = f2bf(v - bf2f(h));
    }
    const size_t halfs = (size_t)nmb * nck * 9 * 128 * 32;
    const size_t base = ((((size_t)mb * nck + ck) * 9 + tap) * 128 + oc) * 32 + oct * 8;
    uint4 vh, vl;
    vh.x = (u32)hh[0] | ((u32)hh[1] << 16); vh.y = (u32)hh[2] | ((u32)hh[3] << 16);
    vh.z = (u32)hh[4] | ((u32)hh[5] << 16); vh.w = (u32)hh[6] | ((u32)hh[7] << 16);
    vl.x = (u32)ll[0] | ((u32)ll[1] << 16); vl.y = (u32)ll[2] | ((u32)ll[3] << 16);
    vl.z = (u32)ll[4] | ((u32)ll[5] << 16); vl.w = (u32)ll[6] | ((u32)ll[7] << 16);
    *(uint4*)(dst + base) = vh;
    *(uint4*)(dst + halfs + base) = vl;
}

// ---------------------------------------------------------------------------
// P4: w12 -> w12p[half][tap][cc][c] split bf16.
// ---------------------------------------------------------------------------
__global__ __launch_bounds__(256) void k_wpack12(
    const float* __restrict__ w12, u16* __restrict__ dst)
{
    const int idx = blockIdx.x * 256 + threadIdx.x;   // 18432
    if (idx >= 18432) return;
    const int oct = idx & 15;
    const int g   = idx >> 4;
    const int cc  = g / 9, tap = g % 9;
    u16 hh[8], ll[8];
#pragma unroll
    for (int j = 0; j < 8; ++j) {
        const float v = w12[(size_t)g * 128 + oct * 8 + j];
        const u16 h = f2bf(v);
        hh[j] = h; ll[j] = f2bf(v - bf2f(h));
    }
    const size_t base = ((size_t)(tap * 128 + cc)) * 128 + oct * 8;
    uint4 vh, vl;
    vh.x = (u32)hh[0] | ((u32)hh[1] << 16); vh.y = (u32)hh[2] | ((u32)hh[3] << 16);
    vh.z = (u32)hh[4] | ((u32)hh[5] << 16); vh.w = (u32)hh[6] | ((u32)hh[7] << 16);
    vl.x = (u32)ll[0] | ((u32)ll[1] << 16); vl.y = (u32)ll[2] | ((u32)ll[3] << 16);
    vl.z = (u32)ll[4] | ((u32)ll[5] << 16); vl.w = (u32)ll[6] | ((u32)ll[7] << 16);
    *(uint4*)(dst + base) = vh;
    *(uint4*)(dst + 147456 + base) = vl;
}

// ---------------------------------------------------------------------------
// 3x3 conv implicit-GEMM MFMA, 2-pass (A split hi/lo, B plain bf16).
// r7-proven schedule: per-ck stage + vmcnt(0) + syncthreads.
// ---------------------------------------------------------------------------
template<int NCK, bool DUAL>
__global__ __launch_bounds__(256, 2) void k_conv_mfma(
    const u16* __restrict__ xin, const u16* __restrict__ wA,
    const float* __restrict__ bias0, const float* __restrict__ bias1,
    const float* __restrict__ bng, const float* __restrict__ bnb,
    const float* __restrict__ bnm, const float* __restrict__ bnv,
    float* __restrict__ dstf, float* __restrict__ bnout,
    u16* __restrict__ y1img)
{
    constexpr int CINP = NCK * 32;
    constexpr size_t WHALF = (size_t)(DUAL ? 2 : 1) * NCK * 9 * 128 * 32;

    __shared__ char smem[32768];   // X: 3 rows x 144cc x 32ch x 2B = 27648B

    const int t    = threadIdx.x;
    const int wave = t >> 6;
    const int lane = t & 63;
    const int wm   = wave >> 1, wn = wave & 1;
    const int y    = yswz(blockIdx.x);
    const int mb   = blockIdx.y;
    const int b    = blockIdx.z;
    const int l15  = lane & 15;
    const int kg   = lane >> 4;

    f32x4 acc[4][4];
    if (DUAL) {
        const float* bp = mb ? bias1 : bias0;
#pragma unroll
        for (int fm = 0; fm < 4; ++fm) {
            const int ocb = wm * 64 + fm * 16 + kg * 4;
#pragma unroll
            for (int j = 0; j < 4; ++j) {
                const float bv = bp[ocb + j];
#pragma unroll
                for (int fn = 0; fn < 4; ++fn) acc[fm][fn][j] = bv;
            }
        }
    } else {
#pragma unroll
        for (int fm = 0; fm < 4; ++fm)
#pragma unroll
            for (int fn = 0; fn < 4; ++fn)
#pragma unroll
                for (int j = 0; j < 4; ++j) acc[fm][fn][j] = 0.0f;
    }

    const size_t xrow = (size_t)130 * CINP;

    for (int ck = 0; ck < NCK; ++ck) {
        __syncthreads();   // prev chunk's LDS reads complete
        for (int idx = wave; idx < 27; idx += 4) {
            const int r = idx / 9, iss = idx % 9;
            const u16* gb = xin + ((size_t)b * 130 + (y + r)) * xrow + ck * 32;
            const int cc = iss * 16 + (lane >> 2);
            const int rb = ((lane & 3) << 4) ^ (xslot(cc) << 4);
            gld_lds16((const char*)gb + (size_t)cc * (CINP * 2) + rb,
                      smem + r * 9216 + iss * 1024);
        }
        asm volatile("s_waitcnt vmcnt(0)" ::: "memory");
        __syncthreads();

        for (int tap = 0; tap < 9; ++tap) {
            const int dy = tap / 3, dx = tap % 3;
            const size_t abase = (((size_t)mb * NCK + ck) * 9 + tap) * 4096;
            bf16x8 ah[4], al[4], bC[4];
#pragma unroll
            for (int f = 0; f < 4; ++f) {
                const size_t ao = abase + (size_t)(wm * 64 + f * 16 + l15) * 32 + kg * 8;
                ah[f] = *(const bf16x8*)(wA + ao);
                al[f] = *(const bf16x8*)(wA + WHALF + ao);
                const int cc = wn * 64 + f * 16 + l15 + dx;
                bC[f] = *(const bf16x8*)(smem + dy * 9216 + cc * 64
                                         + ((kg ^ xslot(cc)) << 4));
            }
#pragma unroll
            for (int fm = 0; fm < 4; ++fm)
#pragma unroll
                for (int fn = 0; fn < 4; ++fn) {
                    acc[fm][fn] = __builtin_amdgcn_mfma_f32_16x16x32_bf16(
                        al[fm], bC[fn], acc[fm][fn], 0, 0, 0);
                    acc[fm][fn] = __builtin_amdgcn_mfma_f32_16x16x32_bf16(
                        ah[fm], bC[fn], acc[fm][fn], 0, 0, 0);
                }
        }
    }

    if (DUAL && mb == 0) {
        // y1: ReLU + RNE bf16 swizzled [px][c] image -> coalesced 32KB store
        __syncthreads();
        u16* img = (u16*)smem;
#pragma unroll
        for (int fm = 0; fm < 4; ++fm)
#pragma unroll
            for (int fn = 0; fn < 4; ++fn) {
                const int px = wn * 64 + fn * 16 + l15;
                const int c0 = wm * 64 + fm * 16 + kg * 4;
                u16 hh[4];
#pragma unroll
                for (int j = 0; j < 4; ++j)
                    hh[j] = f2bf(fmaxf(acc[fm][fn][j], 0.0f));
                const u32 off = swz((u32)(px * 256 + c0 * 2));
                uint2 vh;
                vh.x = (u32)hh[0] | ((u32)hh[1] << 16);
                vh.y = (u32)hh[2] | ((u32)hh[3] << 16);
                *(uint2*)((char*)img + off) = vh;
            }
        __syncthreads();
        uint4* gd = (uint4*)(y1img + ((size_t)b * 128 + y) * 16384);
        const uint4* s4 = (const uint4*)smem;
        for (int i = t; i < 2048; i += 256) gd[i] = s4[i];
        return;
    }

    // fp32 paths (DUAL mb=1 -> y2o; !DUAL -> BN+ReLU -> out)
    float* dst = DUAL ? dstf : bnout;
#pragma unroll
    for (int fm = 0; fm < 4; ++fm) {
#pragma unroll
        for (int j = 0; j < 4; ++j) {
            const int oc = wm * 64 + fm * 16 + kg * 4 + j;
            float sc = 1.0f, sh = 0.0f;
            if (!DUAL) {
                sc = bng[oc] * rsqrtf(bnv[oc] + EPSN);
                sh = bnb[oc] - bnm[oc] * sc;
            }
            const size_t obase = ((size_t)b * CI + oc) * PP + (size_t)y * WW;
#pragma unroll
            for (int fn = 0; fn < 4; ++fn) {
                const int px = wn * 64 + fn * 16 + l15;
                float v = acc[fm][fn][j];
                if (!DUAL) v = fmaf(v, sc, sh);
                dst[obase + px] = fmaxf(v, 0.0f);
            }
        }
    }
}

// ---------------------------------------------------------------------------
// K2: global average pool of y2 -> pooled[b][c]
// ---------------------------------------------------------------------------
__global__ __launch_bounds__(256) void k_pool(
    const float* __restrict__ y2, float* __restrict__ pooled)
{
    const int c = blockIdx.x, b = blockIdx.y, t = threadIdx.x;
    const float* src = y2 + ((size_t)b * CI + c) * PP;
    float s = 0.0f;
    for (int i = t; i < PP; i += 256) s += src[i];
    __shared__ float red[256];
    red[t] = s;
    __syncthreads();
    for (int st = 128; st > 0; st >>= 1) {
        if (t < st) red[t] += red[t + st];
        __syncthreads();
    }
    if (t == 0) pooled[b * CI + c] = red[0] * (1.0f / PP);
}

// ---------------------------------------------------------------------------
// K3: w22o = w22 . pooled + b22 -> split bf16 [half][b][i][j]
// ---------------------------------------------------------------------------
__global__ __launch_bounds__(256) void k_w22(
    const float* __restrict__ w22, const float* __restrict__ b22,
    const float* __restrict__ pooled, u16* __restrict__ w22p)
{
    const int b = blockIdx.y;
    const int o = blockIdx.x * 256 + threadIdx.x;
    __shared__ float pl[CI];
    if (threadIdx.x < CI) pl[threadIdx.x] = pooled[b * CI + threadIdx.x];
    __syncthreads();
    const float4* wr = (const float4*)(w22 + (size_t)o * CI);
    float acc = b22[o];
#pragma unroll 8
    for (int c4 = 0; c4 < CI / 4; ++c4) {
        const float4 w = wr[c4];
        acc += w.x * pl[c4 * 4 + 0] + w.y * pl[c4 * 4 + 1] +
               w.z * pl[c4 * 4 + 2] + w.w * pl[c4 * 4 + 3];
    }
    const u16 h = f2bf(acc);
    w22p[(size_t)b * 16384 + o] = h;
    w22p[65536 + (size_t)b * 16384 + o] = f2bf(acc - bf2f(h));
}

// ---------------------------------------------------------------------------
// K4: guided conv via MFMA (2-pass) + fold reading bf16 NHWC padded image
// (coalesced 8B per 4-ci group, halo = zero pad), BN1+ReLU -> locp image.
// ---------------------------------------------------------------------------
__global__ __launch_bounds__(256, 2) void k_guided_mfma(
    const u16* __restrict__ xpad,    // [b][rr][cc][192] padded bf16 NHWC
    const u16* __restrict__ y1img,   // [b][y][16384] swz image
    const u16* __restrict__ w12p,    // [half +147456][tap][cc][c]
    const float* __restrict__ b12,
    const float* __restrict__ g1, const float* __restrict__ be1,
    const float* __restrict__ m1, const float* __restrict__ v1,
    u16* __restrict__ locp)          // same image format
{
    __shared__ char smem[32768];
    const int t = threadIdx.x;
    const int wave = t >> 6, lane = t & 63;
    const int wm = wave >> 1, wn = wave & 1;
    const int l15 = lane & 15, kg = lane >> 4;
    const int y = yswz(blockIdx.x), b = blockIdx.y;

    {
        const u16* gb = y1img + ((size_t)b * 128 + y) * 16384;
        for (int iss = wave; iss < 32; iss += 4)
            gld_lds16((const char*)gb + iss * 1024 + lane * 16,
                      smem + iss * 1024);
    }
    asm volatile("s_waitcnt vmcnt(0)" ::: "memory");
    __syncthreads();

    f32x4 accL[4][4];
#pragma unroll
    for (int fm = 0; fm < 4; ++fm)
#pragma unroll
        for (int fn = 0; fn < 4; ++fn)
#pragma unroll
            for (int j = 0; j < 4; ++j) accL[fm][fn][j] = 0.0f;

    const u16* xpb = xpad + (size_t)b * 130 * 130 * CIN;

    for (int tap = 0; tap < 9; ++tap) {
        const int dy  = tap / 3;           // padded row rr = y + dy
        const int dxc = tap % 3;           // padded col cc = px + dxc
        if ((unsigned)(y + dy - 1) >= (unsigned)HH) continue;   // x-row all-zero

        f32x4 accG[4][4];
#pragma unroll
        for (int fm = 0; fm < 4; ++fm) {
            float bv[4];
#pragma unroll
            for (int j = 0; j < 4; ++j)
                bv[j] = b12[(wm * 64 + fm * 16 + kg * 4 + j) * 9 + tap];
#pragma unroll
            for (int fn = 0; fn < 4; ++fn)
#pragma unroll
                for (int j = 0; j < 4; ++j) accG[fm][fn][j] = bv[j];
        }

#pragma unroll
        for (int ks = 0; ks < 4; ++ks) {
            bf16x8 bC[4];
#pragma unroll
            for (int f = 0; f < 4; ++f) {
                const int px = wn * 64 + f * 16 + l15;
                bC[f] = *(const bf16x8*)(smem +
                    swz((u32)(px * 256 + ks * 64 + kg * 16)));
            }
#pragma unroll
            for (int fm = 0; fm < 4; ++fm) {
                const size_t ao = ((size_t)(tap * 128 + wm * 64 + fm * 16 + l15)) * 128
                                  + ks * 32 + kg * 8;
                const bf16x8 ah = *(const bf16x8*)(w12p + ao);
                const bf16x8 al = *(const bf16x8*)(w12p + 147456 + ao);
#pragma unroll
                for (int fn = 0; fn < 4; ++fn) {
                    accG[fm][fn] = __builtin_amdgcn_mfma_f32_16x16x32_bf16(
                        al, bC[fn], accG[fm][fn], 0, 0, 0);
                    accG[fm][fn] = __builtin_amdgcn_mfma_f32_16x16x32_bf16(
                        ah, bC[fn], accG[fm][fn], 0, 0, 0);
                }
            }
        }

        // fold: accL += G_k * x[ci][y+dy-1][px+dxc-1] via NHWC bf16 image.
        // Thread's 4 ci are contiguous -> one 8B load per (fm,fn).
#pragma unroll
        for (int fn = 0; fn < 4; ++fn) {
            const int px = wn * 64 + fn * 16 + l15;
            const u16* xp = xpb + ((size_t)(y + dy) * 130 + (px + dxc)) * CIN
                          + wm * 64 + kg * 4;
#pragma unroll
            for (int fm = 0; fm < 4; ++fm) {
                union { uint2 v; u16 s[4]; } xv;
                xv.v = *(const uint2*)(xp + fm * 16);
#pragma unroll
                for (int j = 0; j < 4; ++j)
                    accL[fm][fn][j] = fmaf(accG[fm][fn][j], bf2f(xv.s[j]),
                                           accL[fm][fn][j]);
            }
        }
    }

    __syncthreads();
    u16* img = (u16*)smem;
#pragma unroll
    for (int fm = 0; fm < 4; ++fm) {
        float sc[4], sh[4];
#pragma unroll
        for (int j = 0; j < 4; ++j) {
            const int cc = wm * 64 + fm * 16 + kg * 4 + j;
            sc[j] = g1[cc] * rsqrtf(v1[cc] + EPSN);
            sh[j] = be1[cc] - m1[cc] * sc[j];
        }
#pragma unroll
        for (int fn = 0; fn < 4; ++fn) {
            const int px = wn * 64 + fn * 16 + l15;
            const int c0 = wm * 64 + fm * 16 + kg * 4;
            u16 hh[4];
#pragma unroll
            for (int j = 0; j < 4; ++j)
                hh[j] = f2bf(fmaxf(fmaf(accL[fm][fn][j], sc[j], sh[j]), 0.0f));
            const u32 off = swz((u32)(px * 256 + c0 * 2));
            uint2 vh;
            vh.x = (u32)hh[0] | ((u32)hh[1] << 16);
            vh.y = (u32)hh[2] | ((u32)hh[3] << 16);
            *(uint2*)((char*)img + off) = vh;
        }
    }
    __syncthreads();
    uint4* gd = (uint4*)(locp + ((size_t)b * 128 + y) * 16384);
    const uint4* s4 = (const uint4*)smem;
    for (int i = t; i < 2048; i += 256) gd[i] = s4[i];
}

// ---------------------------------------------------------------------------
// K5: channel-mix bmm via MFMA (2-pass) + BN2 + ReLU -> xpad3 interior
// ---------------------------------------------------------------------------
__global__ __launch_bounds__(256, 2) void k_bmm_mfma(
    const u16* __restrict__ locp, const u16* __restrict__ w22p,
    const float* __restrict__ g2, const float* __restrict__ be2,
    const float* __restrict__ m2, const float* __restrict__ v2,
    u16* __restrict__ x3)
{
    __shared__ char smem[32768];
    const int t = threadIdx.x;
    const int wave = t >> 6, lane = t & 63;
    const int wm = wave >> 1, wn = wave & 1;
    const int l15 = lane & 15, kg = lane >> 4;
    const int y = blockIdx.x, b = blockIdx.y;

    {
        const u16* gb = locp + ((size_t)b * 128 + y) * 16384;
        for (int iss = wave; iss < 32; iss += 4)
            gld_lds16((const char*)gb + iss * 1024 + lane * 16,
                      smem + iss * 1024);
    }
    asm volatile("s_waitcnt vmcnt(0)" ::: "memory");
    __syncthreads();

    f32x4 acc[4][4];
#pragma unroll
    for (int fm = 0; fm < 4; ++fm)
#pragma unroll
        for (int fn = 0; fn < 4; ++fn)
#pragma unroll
            for (int j = 0; j < 4; ++j) acc[fm][fn][j] = 0.0f;

#pragma unroll
    for (int ks = 0; ks < 4; ++ks) {
        bf16x8 bC[4];
#pragma unroll
        for (int f = 0; f < 4; ++f) {
            const int px = wn * 64 + f * 16 + l15;
            bC[f] = *(const bf16x8*)(smem +
                swz((u32)(px * 256 + ks * 64 + kg * 16)));
        }
#pragma unroll
        for (int fm = 0; fm < 4; ++fm) {
            const size_t ao = ((size_t)(b * 128 + wm * 64 + fm * 16 + l15)) * 128
                              + ks * 32 + kg * 8;
            const bf16x8 ah = *(const bf16x8*)(w22p + ao);
            const bf16x8 al = *(const bf16x8*)(w22p + 65536 + ao);
#pragma unroll
            for (int fn = 0; fn < 4; ++fn) {
                acc[fm][fn] = __builtin_amdgcn_mfma_f32_16x16x32_bf16(
                    al, bC[fn], acc[fm][fn], 0, 0, 0);
                acc[fm][fn] = __builtin_amdgcn_mfma_f32_16x16x32_bf16(
                    ah, bC[fn], acc[fm][fn], 0, 0, 0);
            }
        }
    }

    __syncthreads();
    u16* img = (u16*)smem;   // LINEAR [px][c] for conv3 staging
#pragma unroll
    for (int fm = 0; fm < 4; ++fm) {
        float sc[4], sh[4];
#pragma unroll
        for (int j = 0; j < 4; ++j) {
            const int cc = wm * 64 + fm * 16 + kg * 4 + j;
            sc[j] = g2[cc] * rsqrtf(v2[cc] + EPSN);
            sh[j] = be2[cc] - m2[cc] * sc[j];
        }
#pragma unroll
        for (int fn = 0; fn < 4; ++fn) {
            const int px = wn * 64 + fn * 16 + l15;
            const int c0 = wm * 64 + fm * 16 + kg * 4;
            u16 hh[4];
#pragma unroll
            for (int j = 0; j < 4; ++j)
                hh[j] = f2bf(fmaxf(fmaf(acc[fm][fn][j], sc[j], sh[j]), 0.0f));
            const u32 off = (u32)(px * 256 + c0 * 2);
            uint2 vh;
            vh.x = (u32)hh[0] | ((u32)hh[1] << 16);
            vh.y = (u32)hh[2] | ((u32)hh[3] << 16);
            *(uint2*)((char*)img + off) = vh;
        }
    }
    __syncthreads();
    uint4* gd = (uint4*)(x3 + (((size_t)b * 130 + y + 1) * 130 + 1) * 128);
    const uint4* s4 = (const uint4*)smem;
    for (int i = t; i < 2048; i += 256) gd[i] = s4[i];
}

// ---------------------------------------------------------------------------
// K5b: zero the halo borders of xpad3 (single buffer).
// ---------------------------------------------------------------------------
__global__ __launch_bounds__(256) void k_zero3(u16* __restrict__ x3)
{
    const int idx = blockIdx.x * 256 + threadIdx.x;
    if (idx >= 132096) return;                    // 4 batches x 33024 u32
    const int b = idx / 33024;
    int r2 = idx % 33024;
    u32* base = (u32*)(x3 + (size_t)b * 2163200);
    if (r2 < 8320)            base[r2] = 0u;                               // row 0
    else if (r2 < 16640)      base[(size_t)129 * 8320 + (r2 - 8320)] = 0u; // row 129
    else {
        const int q = r2 - 16640;                 // 128 rows x 2 sides x 64 u32
        const int w = q & 63;
        const int r = q >> 6;
        const int row = 1 + (r >> 1);
        const int side = r & 1;
        base[(size_t)row * 8320 + (side ? 8256 : 0) + w] = 0u;
    }
}

// ---------------------------------------------------------------------------
extern "C" void kernel_launch(void* const* d_in, const int* in_sizes, int n_in,
                              void* d_out, int out_size, void* d_ws, size_t ws_size,
                              hipStream_t stream)
{
    (void)in_sizes; (void)n_in; (void)out_size; (void)ws_size;

    const float* input  = (const float*)d_in[0];
    const float* weight = (const float*)d_in[1];
    const float* w11    = (const float*)d_in[2];
    const float* b11    = (const float*)d_in[3];
    const float* w12    = (const float*)d_in[4];
    const float* b12    = (const float*)d_in[5];
    const float* w21    = (const float*)d_in[6];
    const float* b21    = (const float*)d_in[7];
    const float* w22    = (const float*)d_in[8];
    const float* b22    = (const float*)d_in[9];
    const float* g1     = (const float*)d_in[10];
    const float* be1    = (const float*)d_in[11];
    const float* m1     = (const float*)d_in[12];
    const float* v1     = (const float*)d_in[13];
    const float* g2     = (const float*)d_in[14];
    const float* be2    = (const float*)d_in[15];
    const float* m2     = (const float*)d_in[16];
    const float* v2     = (const float*)d_in[17];
    const float* w3     = (const float*)d_in[18];
    const float* g3     = (const float*)d_in[19];
    const float* be3    = (const float*)d_in[20];
    const float* m3     = (const float*)d_in[21];
    const float* v3     = (const float*)d_in[22];

    // Workspace (float offsets), total ~96MB. xpadD stays LIVE through guided
    // (fold reads it); locp has its own region; x3 aliases xpadD (dead after
    // guided, stream-ordered).
    float* ws     = (float*)d_ws;
    float* y2o    = ws;                        // +8388608
    float* pooled = ws + 8388608;              // +512
    u16*   w22p   = (u16*)(ws + 8389120);      // +65536 fl (131072 u16)
    u16*   wAd    = (u16*)(ws + 8454656);      // +442368 fl
    u16*   wA3    = (u16*)(ws + 8897024);      // +147456 fl
    u16*   w12p   = (u16*)(ws + 9044480);      // +147456 fl
    u16*   xpadD  = (u16*)(ws + 9191936);      // +6489600 fl (12979200 u16)
    u16*   x3     = (u16*)(ws + 9191936);      // aliases xpadD (dead post-guided)
    u16*   y1img  = (u16*)(ws + 15681536);     // +4194304 fl (8388608 u16)
    u16*   locp   = (u16*)(ws + 19875840);     // +4194304 fl (8388608 u16)
    float* outp   = (float*)d_out;

    k_pack<<<dim3(130, BB), 256, 0, stream>>>(input, CI, weight, CG, xpadD, CIN);
    k_wpack<<<dim3(216), 256, 0, stream>>>(w11, w21, wAd, 2, 6, CIN);
    k_wpack<<<dim3(72), 256, 0, stream>>>(w3, w3, wA3, 1, 4, CI);
    k_wpack12<<<dim3(72), 256, 0, stream>>>(w12, w12p);

    k_conv_mfma<6, true><<<dim3(128, 2, BB), 256, 0, stream>>>(
        xpadD, wAd, b11, b21, nullptr, nullptr, nullptr, nullptr,
        y2o, nullptr, y1img);

    k_pool<<<dim3(CI, BB), 256, 0, stream>>>(y2o, pooled);
    k_w22<<<dim3(64, BB), 256, 0, stream>>>(w22, b22, pooled, w22p);

    k_guided_mfma<<<dim3(128, BB), 256, 0, stream>>>(
        xpadD, y1img, w12p, b12, g1, be1, m1, v1, locp);

    k_zero3<<<dim3(516), 256, 0, stream>>>(x3);

    k_bmm_mfma<<<dim3(128, BB), 256, 0, stream>>>(
        locp, w22p, g2, be2, m2, v2, x3);

    k_conv_mfma<4, false><<<dim3(128, 1, BB), 256, 0, stream>>>(
        x3, wA3, nullptr, nullptr, g3, be3, m3, v3, nullptr, outp, nullptr);
}